// Round 1
// baseline (488.339 us; speedup 1.0000x reference)
//
#include <hip/hip_runtime.h>
#include <math.h>

#define NB   8
#define NW   200
#define NK   100
#define KSZ  7
#define NHID 150
#define NFE  400
#define NTE  200
#define NG   450   // 3*HID
#define NCIN 300   // 3*K
#define ALPHAC 0.2f

__device__ __forceinline__ float sigmoidf_(float x){ return 1.0f/(1.0f+expf(-x)); }

// ---------------- weight transposes ----------------
__global__ void prep_kernel(const float* conv_w, const float* w_ih, const float* w_hh,
                            float* conv_wT, float* w_ihT, float* w_hhT){
  int idx = blockIdx.x*256 + threadIdx.x;
  const int n1 = NK*NK*KSZ;      // 70000
  const int n2 = NG*NCIN;        // 135000
  const int n3 = NG*NHID;        // 67500
  if (idx < n1){
    int k = idx % NK; int it = idx / NK;       // it = i*KSZ + t
    int i = it / KSZ, t = it % KSZ;
    conv_wT[idx] = conv_w[(k*NK + i)*KSZ + t];
  } else if (idx < n1 + n2){
    int o = idx - n1; int g = o % NG; int c = o / NG;
    w_ihT[o] = w_ih[g*NCIN + c];
  } else if (idx < n1 + n2 + n3){
    int o = idx - n1 - n2; int g = o % NG; int j = o / NG;
    w_hhT[o] = w_hh[g*NHID + j];
  }
}

// ---------------- conv1d + bias + relu -> xc (B,W,K) ----------------
__global__ void conv_kernel(const float* x, const float* conv_b, const float* conv_wT, float* xc){
  int idx = blockIdx.x*256 + threadIdx.x;
  if (idx >= NB*NW*NK) return;
  int k = idx % NK; int w = (idx/NK) % NW; int b = idx/(NK*NW);
  float acc = conv_b[k];
  const float* xb = x + b*NW*NK;
  for (int t = 0; t < KSZ; ++t){
    int ws = w + t - 3;
    if (ws < 0 || ws >= NW) continue;
    const float* xr = xb + ws*NK;
    const float* wr = conv_wT + t*NK + k;   // (i*KSZ+t)*NK + k
    #pragma unroll 4
    for (int i = 0; i < NK; ++i){
      acc += xr[i] * wr[i*KSZ*NK];
    }
  }
  xc[idx] = fmaxf(acc, 0.0f);
}

// ---------------- f-GAT si/sj: (B,K,FE), nodes=features, v[b,n,d]=xc[b,d,n] ----------------
__global__ void fgat_sisj(const float* xc, const float* f_lin_w, float* si, float* sj){
  __shared__ __align__(16) float vt[NW*4];
  int b = blockIdx.x / 25; int n0 = (blockIdx.x % 25)*4;
  int tid = threadIdx.x;
  for (int idx = tid; idx < NW*4; idx += 512){
    int d = idx >> 2, nn = idx & 3;
    vt[idx] = xc[(b*NW + d)*NK + n0 + nn];
  }
  __syncthreads();
  if (tid >= NFE) return;
  int e = tid;
  float a1[4] = {0,0,0,0}, a2[4] = {0,0,0,0};
  for (int d = 0; d < NW; ++d){
    float w1 = f_lin_w[d*NFE + e];
    float w2 = f_lin_w[(NW + d)*NFE + e];
    float4 v = *(const float4*)&vt[d*4];
    a1[0] += v.x*w1; a1[1] += v.y*w1; a1[2] += v.z*w1; a1[3] += v.w*w1;
    a2[0] += v.x*w2; a2[1] += v.y*w2; a2[2] += v.z*w2; a2[3] += v.w*w2;
  }
  #pragma unroll
  for (int nn = 0; nn < 4; ++nn){
    si[(b*NK + n0+nn)*NFE + e] = a1[nn];
    sj[(b*NK + n0+nn)*NFE + e] = a2[nn];
  }
}

// ---------------- t-GAT si/sj: (B,W,TE), nodes=time, v[b,n,d]=xc[b,n,d] ----------------
__global__ void tgat_sisj(const float* xc, const float* t_lin_w, float* si, float* sj){
  __shared__ __align__(16) float vt[NK*4];
  int b = blockIdx.x / 50; int n0 = (blockIdx.x % 50)*4;
  int tid = threadIdx.x;
  for (int idx = tid; idx < NK*4; idx += 256){
    int d = idx >> 2, nn = idx & 3;
    vt[idx] = xc[(b*NW + n0+nn)*NK + d];
  }
  __syncthreads();
  if (tid >= NTE) return;
  int e = tid;
  float a1[4] = {0,0,0,0}, a2[4] = {0,0,0,0};
  for (int d = 0; d < NK; ++d){
    float w1 = t_lin_w[d*NTE + e];
    float w2 = t_lin_w[(NK + d)*NTE + e];
    float4 v = *(const float4*)&vt[d*4];
    a1[0] += v.x*w1; a1[1] += v.y*w1; a1[2] += v.z*w1; a1[3] += v.w*w1;
    a2[0] += v.x*w2; a2[1] += v.y*w2; a2[2] += v.z*w2; a2[3] += v.w*w2;
  }
  #pragma unroll
  for (int nn = 0; nn < 4; ++nn){
    si[(b*NW + n0+nn)*NTE + e] = a1[nn];
    sj[(b*NW + n0+nn)*NTE + e] = a2[nn];
  }
}

// ---------------- f-GAT attention fused: e -> softmax -> sigmoid(attn@v) ----------------
// out written transposed into (B,W,K): h_featT[b,d,i]
__global__ void fgat_attn(const float* xc, const float* si, const float* sj,
                          const float* f_lin_b, const float* f_a, const float* f_bias,
                          float* h_featT){
  __shared__ float sib[NFE], av[NFE], attn[NK], red[128];
  int b = blockIdx.x / NK, i = blockIdx.x % NK;
  int tid = threadIdx.x;
  for (int e = tid; e < NFE; e += 128){
    sib[e] = si[(b*NK + i)*NFE + e] + f_lin_b[e];
    av[e]  = f_a[e];
  }
  __syncthreads();
  float ej = -1e30f;
  if (tid < NK){
    const float* sjr = sj + (b*NK + tid)*NFE;
    float acc = 0.f;
    for (int e = 0; e < NFE; ++e){
      float tv = sib[e] + sjr[e];
      float lk = fmaxf(tv, 0.f) + ALPHAC*fminf(tv, 0.f);
      acc += av[e]*lk;
    }
    ej = acc + f_bias[i*NK + tid];
  }
  red[tid] = ej; __syncthreads();
  for (int s = 64; s > 0; s >>= 1){ if (tid < s) red[tid] = fmaxf(red[tid], red[tid+s]); __syncthreads(); }
  float m = red[0]; __syncthreads();
  float ex = (tid < NK) ? expf(ej - m) : 0.f;
  red[tid] = ex; __syncthreads();
  for (int s = 64; s > 0; s >>= 1){ if (tid < s) red[tid] += red[tid+s]; __syncthreads(); }
  float denom = red[0];
  if (tid < NK) attn[tid] = ex / denom;
  __syncthreads();
  for (int d = tid; d < NW; d += 128){
    const float* xr = xc + (b*NW + d)*NK;    // v[b,j,d] = xc[b,d,j]
    float acc = 0.f;
    for (int j = 0; j < NK; ++j) acc += attn[j]*xr[j];
    h_featT[(b*NW + d)*NK + i] = sigmoidf_(acc);
  }
}

// ---------------- t-GAT attention fused -> h_temp (B,W,K) ----------------
__global__ void tgat_attn(const float* xc, const float* si, const float* sj,
                          const float* t_lin_b, const float* t_a, const float* t_bias,
                          float* h_temp){
  __shared__ float sib[NTE], av[NTE], attn[NW], red[256];
  int b = blockIdx.x / NW, i = blockIdx.x % NW;
  int tid = threadIdx.x;
  for (int e = tid; e < NTE; e += 256){
    sib[e] = si[(b*NW + i)*NTE + e] + t_lin_b[e];
    av[e]  = t_a[e];
  }
  __syncthreads();
  float ej = -1e30f;
  if (tid < NW){
    const float* sjr = sj + (b*NW + tid)*NTE;
    float acc = 0.f;
    for (int e = 0; e < NTE; ++e){
      float tv = sib[e] + sjr[e];
      float lk = fmaxf(tv, 0.f) + ALPHAC*fminf(tv, 0.f);
      acc += av[e]*lk;
    }
    ej = acc + t_bias[i*NW + tid];
  }
  red[tid] = ej; __syncthreads();
  for (int s = 128; s > 0; s >>= 1){ if (tid < s) red[tid] = fmaxf(red[tid], red[tid+s]); __syncthreads(); }
  float m = red[0]; __syncthreads();
  float ex = (tid < NW) ? expf(ej - m) : 0.f;
  red[tid] = ex; __syncthreads();
  for (int s = 128; s > 0; s >>= 1){ if (tid < s) red[tid] += red[tid+s]; __syncthreads(); }
  float denom = red[0];
  if (tid < NW) attn[tid] = ex / denom;
  __syncthreads();
  for (int d = tid; d < NK; d += 256){
    float acc = 0.f;
    for (int j = 0; j < NW; ++j) acc += attn[j]*xc[(b*NW + j)*NK + d];
    h_temp[(b*NW + i)*NK + d] = sigmoidf_(acc);
  }
}

// ---------------- gi = h_cat @ w_ih^T + b_ih, layout (t, b, g) ----------------
__global__ void gi_kernel(const float* xc, const float* h_featT, const float* h_temp,
                          const float* w_ihT, const float* b_ih, float* gi){
  __shared__ __align__(16) float hc[NCIN*8];   // [c][tt], stride 8
  int b = blockIdx.x / 25; int t0 = (blockIdx.x % 25)*8;
  int tid = threadIdx.x;
  for (int idx = tid; idx < NCIN*8; idx += 512){
    int tt = idx / NCIN; int c = idx % NCIN;
    int base = (b*NW + t0 + tt)*NK;
    float v;
    if (c < NK)        v = xc[base + c];
    else if (c < 2*NK) v = h_featT[base + c - NK];
    else               v = h_temp[base + c - 2*NK];
    hc[c*8 + tt] = v;
  }
  __syncthreads();
  if (tid >= NG) return;
  int g = tid;
  float bi = b_ih[g];
  float acc[8];
  #pragma unroll
  for (int tt = 0; tt < 8; ++tt) acc[tt] = bi;
  for (int c = 0; c < NCIN; ++c){
    float wv = w_ihT[c*NG + g];
    float4 h0 = *(const float4*)&hc[c*8];
    float4 h1 = *(const float4*)&hc[c*8+4];
    acc[0] += h0.x*wv; acc[1] += h0.y*wv; acc[2] += h0.z*wv; acc[3] += h0.w*wv;
    acc[4] += h1.x*wv; acc[5] += h1.y*wv; acc[6] += h1.z*wv; acc[7] += h1.w*wv;
  }
  #pragma unroll
  for (int tt = 0; tt < 8; ++tt)
    gi[((t0+tt)*NB + b)*NG + g] = acc[tt];
}

// ---------------- sequential GRU, one block per batch ----------------
__global__ void __launch_bounds__(512) gru_kernel(const float* gi, const float* w_hhT,
                                                  const float* b_hh, float* out){
  __shared__ __align__(16) float h[152];
  __shared__ float gh[NG];
  int b = blockIdx.x; int tid = threadIdx.x;
  float wreg[152];
  float bh = 0.f;
  if (tid < NG){
    bh = b_hh[tid];
    #pragma unroll
    for (int j = 0; j < 152; ++j)
      wreg[j] = (j < NHID) ? w_hhT[j*NG + tid] : 0.f;
  } else {
    #pragma unroll
    for (int j = 0; j < 152; ++j) wreg[j] = 0.f;
  }
  if (tid < 152) h[tid] = 0.f;
  __syncthreads();
  for (int t = 0; t < NW; ++t){
    if (tid < NG){
      float acc = bh;
      #pragma unroll
      for (int j4 = 0; j4 < 38; ++j4){
        float4 hv = *(const float4*)&h[j4*4];
        acc += wreg[j4*4+0]*hv.x + wreg[j4*4+1]*hv.y
             + wreg[j4*4+2]*hv.z + wreg[j4*4+3]*hv.w;
      }
      gh[tid] = acc;
    }
    __syncthreads();
    if (tid < NHID){
      const float* gir = gi + (t*NB + b)*NG;
      float r = sigmoidf_(gir[tid]          + gh[tid]);
      float z = sigmoidf_(gir[NHID + tid]   + gh[NHID + tid]);
      float n = tanhf   (gir[2*NHID + tid]  + r*gh[2*NHID + tid]);
      h[tid] = (1.f - z)*n + z*h[tid];
    }
    __syncthreads();
  }
  if (tid < NHID) out[b*NHID + tid] = h[tid];
}

extern "C" void kernel_launch(void* const* d_in, const int* in_sizes, int n_in,
                              void* d_out, int out_size, void* d_ws, size_t ws_size,
                              hipStream_t stream){
  const float* x       = (const float*)d_in[0];
  const float* conv_w  = (const float*)d_in[1];
  const float* conv_b  = (const float*)d_in[2];
  const float* f_lin_w = (const float*)d_in[3];
  const float* f_lin_b = (const float*)d_in[4];
  const float* f_a     = (const float*)d_in[5];
  const float* f_bias  = (const float*)d_in[6];
  const float* t_lin_w = (const float*)d_in[7];
  const float* t_lin_b = (const float*)d_in[8];
  const float* t_a     = (const float*)d_in[9];
  const float* t_bias  = (const float*)d_in[10];
  const float* w_ih    = (const float*)d_in[11];
  const float* w_hh    = (const float*)d_in[12];
  const float* b_ih    = (const float*)d_in[13];
  const float* b_hh    = (const float*)d_in[14];

  float* ws      = (float*)d_ws;
  float* xc      = ws;               // 160000
  float* conv_wT = ws + 160000;      // 70000
  float* si_f    = ws + 230000;      // 320000
  float* sj_f    = ws + 550000;      // 320000
  float* h_featT = ws + 870000;      // 160000
  float* si_t    = ws + 1030000;     // 320000
  float* sj_t    = ws + 1350000;     // 320000
  float* h_temp  = ws + 1670000;     // 160000
  float* w_ihT   = ws + 1830000;     // 135000
  float* gi      = ws + 1965000;     // 720000
  float* w_hhT   = ws + 2685000;     // 67500
                                     // total 2752500 floats ~= 11 MB

  prep_kernel<<<1065, 256, 0, stream>>>(conv_w, w_ih, w_hh, conv_wT, w_ihT, w_hhT);
  conv_kernel<<<(NB*NW*NK + 255)/256, 256, 0, stream>>>(x, conv_b, conv_wT, xc);
  fgat_sisj<<<NB*25, 512, 0, stream>>>(xc, f_lin_w, si_f, sj_f);
  tgat_sisj<<<NB*50, 256, 0, stream>>>(xc, t_lin_w, si_t, sj_t);
  fgat_attn<<<NB*NK, 128, 0, stream>>>(xc, si_f, sj_f, f_lin_b, f_a, f_bias, h_featT);
  tgat_attn<<<NB*NW, 256, 0, stream>>>(xc, si_t, sj_t, t_lin_b, t_a, t_bias, h_temp);
  gi_kernel<<<NB*25, 512, 0, stream>>>(xc, h_featT, h_temp, w_ihT, b_ih, gi);
  gru_kernel<<<NB, 512, 0, stream>>>(gi, w_hhT, b_hh, (float*)d_out);
}

// Round 2
// 425.230 us; speedup vs baseline: 1.1484x; 1.1484x over previous
//
#include <hip/hip_runtime.h>
#include <math.h>

#define NB   8
#define NW   200
#define NK   100
#define KSZ  7
#define NHID 150
#define NFE  400
#define NTE  200
#define NG   450   // 3*HID
#define NCIN 300   // 3*K
#define ALPHAC 0.2f

__device__ __forceinline__ float sigmoidf_(float x){
  return 1.0f/(1.0f + __expf(-x));
}
__device__ __forceinline__ float tanhf_(float x){
  float xc = fminf(fmaxf(x, -15.f), 15.f);
  float e = __expf(2.f*xc);
  return (e - 1.f)/(e + 1.f);
}

// ---------------- weight transposes ----------------
__global__ void prep_kernel(const float* conv_w, const float* w_ih, const float* w_hh,
                            float* conv_wT, float* w_ihT, float* w_hhT){
  int idx = blockIdx.x*256 + threadIdx.x;
  const int n1 = NK*NK*KSZ;      // 70000
  const int n2 = NG*NCIN;        // 135000
  const int n3 = 150*512;        // 76800 (padded: [j][g] stride 512)
  if (idx < n1){
    int k = idx % NK; int it = idx / NK;       // it = i*KSZ + t
    int i = it / KSZ, t = it % KSZ;
    conv_wT[idx] = conv_w[(k*NK + i)*KSZ + t];
  } else if (idx < n1 + n2){
    int o = idx - n1; int g = o % NG; int c = o / NG;
    w_ihT[o] = w_ih[g*NCIN + c];
  } else if (idx < n1 + n2 + n3){
    int o = idx - n1 - n2; int g = o % 512; int j = o / 512;
    w_hhT[o] = (g < NG) ? w_hh[g*NHID + j] : 0.f;
  }
}

// ---------------- conv1d + bias + relu -> xc (B,W,K) ----------------
__global__ void conv_kernel(const float* x, const float* conv_b, const float* conv_wT, float* xc){
  int idx = blockIdx.x*256 + threadIdx.x;
  if (idx >= NB*NW*NK) return;
  int k = idx % NK; int w = (idx/NK) % NW; int b = idx/(NK*NW);
  float acc = conv_b[k];
  const float* xb = x + b*NW*NK;
  for (int t = 0; t < KSZ; ++t){
    int ws = w + t - 3;
    if (ws < 0 || ws >= NW) continue;
    const float* xr = xb + ws*NK;
    const float* wr = conv_wT + t*NK + k;   // (i*KSZ+t)*NK + k
    #pragma unroll 4
    for (int i = 0; i < NK; ++i){
      acc += xr[i] * wr[i*KSZ*NK];
    }
  }
  xc[idx] = fmaxf(acc, 0.0f);
}

// ---------------- f-GAT si/sj: (B,K,FE), nodes=features, v[b,n,d]=xc[b,d,n] ----------------
__global__ void fgat_sisj(const float* xc, const float* f_lin_w, float* si, float* sj){
  __shared__ __align__(16) float vt[NW*4];
  int b = blockIdx.x / 25; int n0 = (blockIdx.x % 25)*4;
  int tid = threadIdx.x;
  for (int idx = tid; idx < NW*4; idx += 512){
    int d = idx >> 2, nn = idx & 3;
    vt[idx] = xc[(b*NW + d)*NK + n0 + nn];
  }
  __syncthreads();
  if (tid >= NFE) return;
  int e = tid;
  float a1[4] = {0,0,0,0}, a2[4] = {0,0,0,0};
  for (int d = 0; d < NW; ++d){
    float w1 = f_lin_w[d*NFE + e];
    float w2 = f_lin_w[(NW + d)*NFE + e];
    float4 v = *(const float4*)&vt[d*4];
    a1[0] += v.x*w1; a1[1] += v.y*w1; a1[2] += v.z*w1; a1[3] += v.w*w1;
    a2[0] += v.x*w2; a2[1] += v.y*w2; a2[2] += v.z*w2; a2[3] += v.w*w2;
  }
  #pragma unroll
  for (int nn = 0; nn < 4; ++nn){
    si[(b*NK + n0+nn)*NFE + e] = a1[nn];
    sj[(b*NK + n0+nn)*NFE + e] = a2[nn];
  }
}

// ---------------- t-GAT si/sj: (B,W,TE), nodes=time, v[b,n,d]=xc[b,n,d] ----------------
__global__ void tgat_sisj(const float* xc, const float* t_lin_w, float* si, float* sj){
  __shared__ __align__(16) float vt[NK*4];
  int b = blockIdx.x / 50; int n0 = (blockIdx.x % 50)*4;
  int tid = threadIdx.x;
  for (int idx = tid; idx < NK*4; idx += 256){
    int d = idx >> 2, nn = idx & 3;
    vt[idx] = xc[(b*NW + n0+nn)*NK + d];
  }
  __syncthreads();
  if (tid >= NTE) return;
  int e = tid;
  float a1[4] = {0,0,0,0}, a2[4] = {0,0,0,0};
  for (int d = 0; d < NK; ++d){
    float w1 = t_lin_w[d*NTE + e];
    float w2 = t_lin_w[(NK + d)*NTE + e];
    float4 v = *(const float4*)&vt[d*4];
    a1[0] += v.x*w1; a1[1] += v.y*w1; a1[2] += v.z*w1; a1[3] += v.w*w1;
    a2[0] += v.x*w2; a2[1] += v.y*w2; a2[2] += v.z*w2; a2[3] += v.w*w2;
  }
  #pragma unroll
  for (int nn = 0; nn < 4; ++nn){
    si[(b*NW + n0+nn)*NTE + e] = a1[nn];
    sj[(b*NW + n0+nn)*NTE + e] = a2[nn];
  }
}

// ---------------- f-GAT attention fused: e -> softmax -> sigmoid(attn@v) ----------------
// out written transposed into (B,W,K): h_featT[b,d,i]
__global__ void fgat_attn(const float* xc, const float* si, const float* sj,
                          const float* f_lin_b, const float* f_a, const float* f_bias,
                          float* h_featT){
  __shared__ float sib[NFE], av[NFE], attn[NK], red[128];
  int b = blockIdx.x / NK, i = blockIdx.x % NK;
  int tid = threadIdx.x;
  for (int e = tid; e < NFE; e += 128){
    sib[e] = si[(b*NK + i)*NFE + e] + f_lin_b[e];
    av[e]  = f_a[e];
  }
  __syncthreads();
  float ej = -1e30f;
  if (tid < NK){
    const float* sjr = sj + (b*NK + tid)*NFE;
    float acc = 0.f;
    for (int e = 0; e < NFE; ++e){
      float tv = sib[e] + sjr[e];
      float lk = fmaxf(tv, 0.f) + ALPHAC*fminf(tv, 0.f);
      acc += av[e]*lk;
    }
    ej = acc + f_bias[i*NK + tid];
  }
  red[tid] = ej; __syncthreads();
  for (int s = 64; s > 0; s >>= 1){ if (tid < s) red[tid] = fmaxf(red[tid], red[tid+s]); __syncthreads(); }
  float m = red[0]; __syncthreads();
  float ex = (tid < NK) ? __expf(ej - m) : 0.f;
  red[tid] = ex; __syncthreads();
  for (int s = 64; s > 0; s >>= 1){ if (tid < s) red[tid] += red[tid+s]; __syncthreads(); }
  float denom = red[0];
  if (tid < NK) attn[tid] = ex / denom;
  __syncthreads();
  for (int d = tid; d < NW; d += 128){
    const float* xr = xc + (b*NW + d)*NK;    // v[b,j,d] = xc[b,d,j]
    float acc = 0.f;
    for (int j = 0; j < NK; ++j) acc += attn[j]*xr[j];
    h_featT[(b*NW + d)*NK + i] = sigmoidf_(acc);
  }
}

// ---------------- t-GAT attention fused -> h_temp (B,W,K) ----------------
__global__ void tgat_attn(const float* xc, const float* si, const float* sj,
                          const float* t_lin_b, const float* t_a, const float* t_bias,
                          float* h_temp){
  __shared__ float sib[NTE], av[NTE], attn[NW], red[256];
  int b = blockIdx.x / NW, i = blockIdx.x % NW;
  int tid = threadIdx.x;
  for (int e = tid; e < NTE; e += 256){
    sib[e] = si[(b*NW + i)*NTE + e] + t_lin_b[e];
    av[e]  = t_a[e];
  }
  __syncthreads();
  float ej = -1e30f;
  if (tid < NW){
    const float* sjr = sj + (b*NW + tid)*NTE;
    float acc = 0.f;
    for (int e = 0; e < NTE; ++e){
      float tv = sib[e] + sjr[e];
      float lk = fmaxf(tv, 0.f) + ALPHAC*fminf(tv, 0.f);
      acc += av[e]*lk;
    }
    ej = acc + t_bias[i*NW + tid];
  }
  red[tid] = ej; __syncthreads();
  for (int s = 128; s > 0; s >>= 1){ if (tid < s) red[tid] = fmaxf(red[tid], red[tid+s]); __syncthreads(); }
  float m = red[0]; __syncthreads();
  float ex = (tid < NW) ? __expf(ej - m) : 0.f;
  red[tid] = ex; __syncthreads();
  for (int s = 128; s > 0; s >>= 1){ if (tid < s) red[tid] += red[tid+s]; __syncthreads(); }
  float denom = red[0];
  if (tid < NW) attn[tid] = ex / denom;
  __syncthreads();
  for (int d = tid; d < NK; d += 256){
    float acc = 0.f;
    for (int j = 0; j < NW; ++j) acc += attn[j]*xc[(b*NW + j)*NK + d];
    h_temp[(b*NW + i)*NK + d] = sigmoidf_(acc);
  }
}

// ---------------- gi = h_cat @ w_ih^T + b_ih, layout (t, b, g) ----------------
__global__ void gi_kernel(const float* xc, const float* h_featT, const float* h_temp,
                          const float* w_ihT, const float* b_ih, float* gi){
  __shared__ __align__(16) float hc[NCIN*8];   // [c][tt], stride 8
  int b = blockIdx.x / 25; int t0 = (blockIdx.x % 25)*8;
  int tid = threadIdx.x;
  for (int idx = tid; idx < NCIN*8; idx += 512){
    int tt = idx / NCIN; int c = idx % NCIN;
    int base = (b*NW + t0 + tt)*NK;
    float v;
    if (c < NK)        v = xc[base + c];
    else if (c < 2*NK) v = h_featT[base + c - NK];
    else               v = h_temp[base + c - 2*NK];
    hc[c*8 + tt] = v;
  }
  __syncthreads();
  if (tid >= NG) return;
  int g = tid;
  float bi = b_ih[g];
  float acc[8];
  #pragma unroll
  for (int tt = 0; tt < 8; ++tt) acc[tt] = bi;
  for (int c = 0; c < NCIN; ++c){
    float wv = w_ihT[c*NG + g];
    float4 h0 = *(const float4*)&hc[c*8];
    float4 h1 = *(const float4*)&hc[c*8+4];
    acc[0] += h0.x*wv; acc[1] += h0.y*wv; acc[2] += h0.z*wv; acc[3] += h0.w*wv;
    acc[4] += h1.x*wv; acc[5] += h1.y*wv; acc[6] += h1.z*wv; acc[7] += h1.w*wv;
  }
  #pragma unroll
  for (int tt = 0; tt < 8; ++tt)
    gi[((t0+tt)*NB + b)*NG + g] = acc[tt];
}

// ---------------- sequential GRU, one block per batch ----------------
// 512 threads, 2 waves/SIMD -> 256-VGPR budget: the 152-float w_hh row
// MUST live in registers (round-1 failure: default heuristic spilled it
// to scratch -> L2-stream-bound, 3720 cyc/step).
__global__ void __launch_bounds__(512, 2) gru_kernel(const float* gi, const float* w_hhT,
                                                     const float* b_hh, float* out){
  __shared__ __align__(16) float h[152];
  __shared__ float gh[512];
  int b = blockIdx.x; int tid = threadIdx.x;
  int gsafe = (tid < NG) ? tid : 0;
  float bh = b_hh[gsafe];
  float wreg[152];
  #pragma unroll
  for (int j = 0; j < 150; ++j)
    wreg[j] = w_hhT[j*512 + tid];           // padded stride-512, all threads load
  wreg[150] = 0.f; wreg[151] = 0.f;
  if (tid < 152) h[tid] = 0.f;
  __syncthreads();
  for (int t = 0; t < NW; ++t){
    // prefetch this step's gi early: latency hides under the matvec
    float p0 = 0.f, p1 = 0.f, p2 = 0.f;
    if (tid < NHID){
      const float* gir = gi + (t*NB + b)*NG;
      p0 = gir[tid]; p1 = gir[NHID + tid]; p2 = gir[2*NHID + tid];
    }
    float acc = bh;
    #pragma unroll
    for (int j4 = 0; j4 < 38; ++j4){
      float4 hv = *(const float4*)&h[j4*4];
      acc += wreg[j4*4+0]*hv.x + wreg[j4*4+1]*hv.y
           + wreg[j4*4+2]*hv.z + wreg[j4*4+3]*hv.w;
    }
    gh[tid] = acc;
    __syncthreads();
    if (tid < NHID){
      float r = sigmoidf_(p0 + gh[tid]);
      float z = sigmoidf_(p1 + gh[NHID + tid]);
      float n = tanhf_  (p2 + r*gh[2*NHID + tid]);
      h[tid] = (1.f - z)*n + z*h[tid];
    }
    __syncthreads();
  }
  if (tid < NHID) out[b*NHID + tid] = h[tid];
}

extern "C" void kernel_launch(void* const* d_in, const int* in_sizes, int n_in,
                              void* d_out, int out_size, void* d_ws, size_t ws_size,
                              hipStream_t stream){
  const float* x       = (const float*)d_in[0];
  const float* conv_w  = (const float*)d_in[1];
  const float* conv_b  = (const float*)d_in[2];
  const float* f_lin_w = (const float*)d_in[3];
  const float* f_lin_b = (const float*)d_in[4];
  const float* f_a     = (const float*)d_in[5];
  const float* f_bias  = (const float*)d_in[6];
  const float* t_lin_w = (const float*)d_in[7];
  const float* t_lin_b = (const float*)d_in[8];
  const float* t_a     = (const float*)d_in[9];
  const float* t_bias  = (const float*)d_in[10];
  const float* w_ih    = (const float*)d_in[11];
  const float* w_hh    = (const float*)d_in[12];
  const float* b_ih    = (const float*)d_in[13];
  const float* b_hh    = (const float*)d_in[14];

  float* ws      = (float*)d_ws;
  float* xc      = ws;               // 160000
  float* conv_wT = ws + 160000;      // 70000
  float* si_f    = ws + 230000;      // 320000
  float* sj_f    = ws + 550000;      // 320000
  float* h_featT = ws + 870000;      // 160000
  float* si_t    = ws + 1030000;     // 320000
  float* sj_t    = ws + 1350000;     // 320000
  float* h_temp  = ws + 1670000;     // 160000
  float* w_ihT   = ws + 1830000;     // 135000
  float* gi      = ws + 1965000;     // 720000
  float* w_hhT   = ws + 2685000;     // 76800 (padded 150x512)
                                     // total 2761800 floats ~= 11.05 MB

  prep_kernel<<<1101, 256, 0, stream>>>(conv_w, w_ih, w_hh, conv_wT, w_ihT, w_hhT);
  conv_kernel<<<(NB*NW*NK + 255)/256, 256, 0, stream>>>(x, conv_b, conv_wT, xc);
  fgat_sisj<<<NB*25, 512, 0, stream>>>(xc, f_lin_w, si_f, sj_f);
  tgat_sisj<<<NB*50, 256, 0, stream>>>(xc, t_lin_w, si_t, sj_t);
  fgat_attn<<<NB*NK, 128, 0, stream>>>(xc, si_f, sj_f, f_lin_b, f_a, f_bias, h_featT);
  tgat_attn<<<NB*NW, 256, 0, stream>>>(xc, si_t, sj_t, t_lin_b, t_a, t_bias, h_temp);
  gi_kernel<<<NB*25, 512, 0, stream>>>(xc, h_featT, h_temp, w_ihT, b_ih, gi);
  gru_kernel<<<NB, 512, 0, stream>>>(gi, w_hhT, b_hh, (float*)d_out);
}

// Round 3
// 391.345 us; speedup vs baseline: 1.2478x; 1.0866x over previous
//
#include <hip/hip_runtime.h>
#include <math.h>

#define NB   8
#define NW   200
#define NK   100
#define KSZ  7
#define NHID 150
#define NFE  400
#define NTE  200
#define NG   450   // 3*HID
#define NCIN 300   // 3*K
#define ALPHAC 0.2f

__device__ __forceinline__ float sigmoidf_(float x){
  return 1.0f/(1.0f + __expf(-x));
}
__device__ __forceinline__ float tanhf_(float x){
  float xc = fminf(fmaxf(x, -15.f), 15.f);
  float e = __expf(2.f*xc);
  return (e - 1.f)/(e + 1.f);
}

// ---------------- weight transposes ----------------
__global__ void prep_kernel(const float* conv_w, const float* w_ih, const float* w_hh,
                            float* conv_wT, float* w_ihT, float* w_hhPad){
  int idx = blockIdx.x*256 + threadIdx.x;
  const int n1 = NK*NK*KSZ;      // 70000
  const int n2 = NG*NCIN;        // 135000
  const int n3 = 152*512;        // 77824 (padded: [j][g] stride 512, j<152)
  if (idx < n1){
    int k = idx % NK; int it = idx / NK;       // it = i*KSZ + t
    int i = it / KSZ, t = it % KSZ;
    conv_wT[idx] = conv_w[(k*NK + i)*KSZ + t];
  } else if (idx < n1 + n2){
    int o = idx - n1; int g = o % NG; int c = o / NG;
    w_ihT[o] = w_ih[g*NCIN + c];
  } else if (idx < n1 + n2 + n3){
    int o = idx - n1 - n2; int g = o % 512; int j = o / 512;
    w_hhPad[o] = (g < NG && j < NHID) ? w_hh[g*NHID + j] : 0.f;
  }
}

// ---------------- conv1d + bias + relu -> xc (B,W,K) ----------------
__global__ void conv_kernel(const float* x, const float* conv_b, const float* conv_wT, float* xc){
  int idx = blockIdx.x*256 + threadIdx.x;
  if (idx >= NB*NW*NK) return;
  int k = idx % NK; int w = (idx/NK) % NW; int b = idx/(NK*NW);
  float acc = conv_b[k];
  const float* xb = x + b*NW*NK;
  for (int t = 0; t < KSZ; ++t){
    int ws = w + t - 3;
    if (ws < 0 || ws >= NW) continue;
    const float* xr = xb + ws*NK;
    const float* wr = conv_wT + t*NK + k;   // (i*KSZ+t)*NK + k
    #pragma unroll 4
    for (int i = 0; i < NK; ++i){
      acc += xr[i] * wr[i*KSZ*NK];
    }
  }
  xc[idx] = fmaxf(acc, 0.0f);
}

// ---------------- f-GAT si/sj: (B,K,FE), nodes=features, v[b,n,d]=xc[b,d,n] ----------------
__global__ void fgat_sisj(const float* xc, const float* f_lin_w, float* si, float* sj){
  __shared__ __align__(16) float vt[NW*4];
  int b = blockIdx.x / 25; int n0 = (blockIdx.x % 25)*4;
  int tid = threadIdx.x;
  for (int idx = tid; idx < NW*4; idx += 512){
    int d = idx >> 2, nn = idx & 3;
    vt[idx] = xc[(b*NW + d)*NK + n0 + nn];
  }
  __syncthreads();
  if (tid >= NFE) return;
  int e = tid;
  float a1[4] = {0,0,0,0}, a2[4] = {0,0,0,0};
  for (int d = 0; d < NW; ++d){
    float w1 = f_lin_w[d*NFE + e];
    float w2 = f_lin_w[(NW + d)*NFE + e];
    float4 v = *(const float4*)&vt[d*4];
    a1[0] += v.x*w1; a1[1] += v.y*w1; a1[2] += v.z*w1; a1[3] += v.w*w1;
    a2[0] += v.x*w2; a2[1] += v.y*w2; a2[2] += v.z*w2; a2[3] += v.w*w2;
  }
  #pragma unroll
  for (int nn = 0; nn < 4; ++nn){
    si[(b*NK + n0+nn)*NFE + e] = a1[nn];
    sj[(b*NK + n0+nn)*NFE + e] = a2[nn];
  }
}

// ---------------- t-GAT si/sj: (B,W,TE), nodes=time, v[b,n,d]=xc[b,n,d] ----------------
__global__ void tgat_sisj(const float* xc, const float* t_lin_w, float* si, float* sj){
  __shared__ __align__(16) float vt[NK*4];
  int b = blockIdx.x / 50; int n0 = (blockIdx.x % 50)*4;
  int tid = threadIdx.x;
  for (int idx = tid; idx < NK*4; idx += 256){
    int d = idx >> 2, nn = idx & 3;
    vt[idx] = xc[(b*NW + n0+nn)*NK + d];
  }
  __syncthreads();
  if (tid >= NTE) return;
  int e = tid;
  float a1[4] = {0,0,0,0}, a2[4] = {0,0,0,0};
  for (int d = 0; d < NK; ++d){
    float w1 = t_lin_w[d*NTE + e];
    float w2 = t_lin_w[(NK + d)*NTE + e];
    float4 v = *(const float4*)&vt[d*4];
    a1[0] += v.x*w1; a1[1] += v.y*w1; a1[2] += v.z*w1; a1[3] += v.w*w1;
    a2[0] += v.x*w2; a2[1] += v.y*w2; a2[2] += v.z*w2; a2[3] += v.w*w2;
  }
  #pragma unroll
  for (int nn = 0; nn < 4; ++nn){
    si[(b*NW + n0+nn)*NTE + e] = a1[nn];
    sj[(b*NW + n0+nn)*NTE + e] = a2[nn];
  }
}

// ---------------- f-GAT attention fused: e -> softmax -> sigmoid(attn@v) ----------------
// out written transposed into (B,W,K): h_featT[b,d,i]
__global__ void fgat_attn(const float* xc, const float* si, const float* sj,
                          const float* f_lin_b, const float* f_a, const float* f_bias,
                          float* h_featT){
  __shared__ float sib[NFE], av[NFE], attn[NK], red[128];
  int b = blockIdx.x / NK, i = blockIdx.x % NK;
  int tid = threadIdx.x;
  for (int e = tid; e < NFE; e += 128){
    sib[e] = si[(b*NK + i)*NFE + e] + f_lin_b[e];
    av[e]  = f_a[e];
  }
  __syncthreads();
  float ej = -1e30f;
  if (tid < NK){
    const float* sjr = sj + (b*NK + tid)*NFE;
    float acc = 0.f;
    for (int e = 0; e < NFE; ++e){
      float tv = sib[e] + sjr[e];
      float lk = fmaxf(tv, 0.f) + ALPHAC*fminf(tv, 0.f);
      acc += av[e]*lk;
    }
    ej = acc + f_bias[i*NK + tid];
  }
  red[tid] = ej; __syncthreads();
  for (int s = 64; s > 0; s >>= 1){ if (tid < s) red[tid] = fmaxf(red[tid], red[tid+s]); __syncthreads(); }
  float m = red[0]; __syncthreads();
  float ex = (tid < NK) ? __expf(ej - m) : 0.f;
  red[tid] = ex; __syncthreads();
  for (int s = 64; s > 0; s >>= 1){ if (tid < s) red[tid] += red[tid+s]; __syncthreads(); }
  float denom = red[0];
  if (tid < NK) attn[tid] = ex / denom;
  __syncthreads();
  for (int d = tid; d < NW; d += 128){
    const float* xr = xc + (b*NW + d)*NK;    // v[b,j,d] = xc[b,d,j]
    float acc = 0.f;
    for (int j = 0; j < NK; ++j) acc += attn[j]*xr[j];
    h_featT[(b*NW + d)*NK + i] = sigmoidf_(acc);
  }
}

// ---------------- t-GAT attention fused -> h_temp (B,W,K) ----------------
__global__ void tgat_attn(const float* xc, const float* si, const float* sj,
                          const float* t_lin_b, const float* t_a, const float* t_bias,
                          float* h_temp){
  __shared__ float sib[NTE], av[NTE], attn[NW], red[256];
  int b = blockIdx.x / NW, i = blockIdx.x % NW;
  int tid = threadIdx.x;
  for (int e = tid; e < NTE; e += 256){
    sib[e] = si[(b*NW + i)*NTE + e] + t_lin_b[e];
    av[e]  = t_a[e];
  }
  __syncthreads();
  float ej = -1e30f;
  if (tid < NW){
    const float* sjr = sj + (b*NW + tid)*NTE;
    float acc = 0.f;
    for (int e = 0; e < NTE; ++e){
      float tv = sib[e] + sjr[e];
      float lk = fmaxf(tv, 0.f) + ALPHAC*fminf(tv, 0.f);
      acc += av[e]*lk;
    }
    ej = acc + t_bias[i*NW + tid];
  }
  red[tid] = ej; __syncthreads();
  for (int s = 128; s > 0; s >>= 1){ if (tid < s) red[tid] = fmaxf(red[tid], red[tid+s]); __syncthreads(); }
  float m = red[0]; __syncthreads();
  float ex = (tid < NW) ? __expf(ej - m) : 0.f;
  red[tid] = ex; __syncthreads();
  for (int s = 128; s > 0; s >>= 1){ if (tid < s) red[tid] += red[tid+s]; __syncthreads(); }
  float denom = red[0];
  if (tid < NW) attn[tid] = ex / denom;
  __syncthreads();
  for (int d = tid; d < NK; d += 256){
    float acc = 0.f;
    for (int j = 0; j < NW; ++j) acc += attn[j]*xc[(b*NW + j)*NK + d];
    h_temp[(b*NW + i)*NK + d] = sigmoidf_(acc);
  }
}

// ---------------- gi = h_cat @ w_ih^T + b_ih, layout (t, b, g) ----------------
__global__ void gi_kernel(const float* xc, const float* h_featT, const float* h_temp,
                          const float* w_ihT, const float* b_ih, float* gi){
  __shared__ __align__(16) float hc[NCIN*8];   // [c][tt], stride 8
  int b = blockIdx.x / 25; int t0 = (blockIdx.x % 25)*8;
  int tid = threadIdx.x;
  for (int idx = tid; idx < NCIN*8; idx += 512){
    int tt = idx / NCIN; int c = idx % NCIN;
    int base = (b*NW + t0 + tt)*NK;
    float v;
    if (c < NK)        v = xc[base + c];
    else if (c < 2*NK) v = h_featT[base + c - NK];
    else               v = h_temp[base + c - 2*NK];
    hc[c*8 + tt] = v;
  }
  __syncthreads();
  if (tid >= NG) return;
  int g = tid;
  float bi = b_ih[g];
  float acc[8];
  #pragma unroll
  for (int tt = 0; tt < 8; ++tt) acc[tt] = bi;
  for (int c = 0; c < NCIN; ++c){
    float wv = w_ihT[c*NG + g];
    float4 h0 = *(const float4*)&hc[c*8];
    float4 h1 = *(const float4*)&hc[c*8+4];
    acc[0] += h0.x*wv; acc[1] += h0.y*wv; acc[2] += h0.z*wv; acc[3] += h0.w*wv;
    acc[4] += h1.x*wv; acc[5] += h1.y*wv; acc[6] += h1.z*wv; acc[7] += h1.w*wv;
  }
  #pragma unroll
  for (int tt = 0; tt < 8; ++tt)
    gi[((t0+tt)*NB + b)*NG + g] = acc[tt];
}

// ---------------- sequential GRU, one block per batch ----------------
// 1024 threads: output g is split across 2 threads (tid = g and 512+g), each
// holding only 19 float4 of w_hh -> small enough that full unroll + SROA
// keeps it in VGPRs (round-2 failure: wreg[152] load loop (150 iters) never
// unrolled -> dynamic indices -> scratch, VGPR_Count stuck at 108).
__global__ void __launch_bounds__(1024, 4) gru_kernel(const float* gi, const float* w_hhPad,
                                                      const float* b_hh, float* out){
  __shared__ __align__(16) float h[152];
  __shared__ float part[1024];
  int b = blockIdx.x; int tid = threadIdx.x;
  int g = tid & 511; int half = tid >> 9;
  int jbase = half*76;
  float bh = (half == 0 && g < NG) ? b_hh[g] : 0.f;
  float4 wreg[19];
  #pragma unroll
  for (int jj = 0; jj < 19; ++jj){
    int j = jbase + jj*4;
    wreg[jj].x = w_hhPad[(j+0)*512 + g];
    wreg[jj].y = w_hhPad[(j+1)*512 + g];
    wreg[jj].z = w_hhPad[(j+2)*512 + g];
    wreg[jj].w = w_hhPad[(j+3)*512 + g];
  }
  if (tid < 152) h[tid] = 0.f;
  __syncthreads();
  for (int t = 0; t < NW; ++t){
    // prefetch this step's gi early: latency hides under the matvec
    float p0 = 0.f, p1 = 0.f, p2 = 0.f;
    if (tid < NHID){
      const float* gir = gi + (t*NB + b)*NG;
      p0 = gir[tid]; p1 = gir[NHID + tid]; p2 = gir[2*NHID + tid];
    }
    float acc = bh;
    #pragma unroll
    for (int jj = 0; jj < 19; ++jj){
      float4 hv = *(const float4*)&h[jbase + jj*4];
      acc += wreg[jj].x*hv.x + wreg[jj].y*hv.y
           + wreg[jj].z*hv.z + wreg[jj].w*hv.w;
    }
    part[tid] = acc;
    __syncthreads();
    if (tid < NHID){
      float ghr = part[tid]       + part[512 + tid];
      float ghz = part[150 + tid] + part[512 + 150 + tid];
      float ghn = part[300 + tid] + part[512 + 300 + tid];
      float r = sigmoidf_(p0 + ghr);
      float z = sigmoidf_(p1 + ghz);
      float n = tanhf_  (p2 + r*ghn);
      h[tid] = (1.f - z)*n + z*h[tid];
    }
    __syncthreads();
  }
  if (tid < NHID) out[b*NHID + tid] = h[tid];
}

extern "C" void kernel_launch(void* const* d_in, const int* in_sizes, int n_in,
                              void* d_out, int out_size, void* d_ws, size_t ws_size,
                              hipStream_t stream){
  const float* x       = (const float*)d_in[0];
  const float* conv_w  = (const float*)d_in[1];
  const float* conv_b  = (const float*)d_in[2];
  const float* f_lin_w = (const float*)d_in[3];
  const float* f_lin_b = (const float*)d_in[4];
  const float* f_a     = (const float*)d_in[5];
  const float* f_bias  = (const float*)d_in[6];
  const float* t_lin_w = (const float*)d_in[7];
  const float* t_lin_b = (const float*)d_in[8];
  const float* t_a     = (const float*)d_in[9];
  const float* t_bias  = (const float*)d_in[10];
  const float* w_ih    = (const float*)d_in[11];
  const float* w_hh    = (const float*)d_in[12];
  const float* b_ih    = (const float*)d_in[13];
  const float* b_hh    = (const float*)d_in[14];

  float* ws      = (float*)d_ws;
  float* xc      = ws;               // 160000
  float* conv_wT = ws + 160000;      // 70000
  float* si_f    = ws + 230000;      // 320000
  float* sj_f    = ws + 550000;      // 320000
  float* h_featT = ws + 870000;      // 160000
  float* si_t    = ws + 1030000;     // 320000
  float* sj_t    = ws + 1350000;     // 320000
  float* h_temp  = ws + 1670000;     // 160000
  float* w_ihT   = ws + 1830000;     // 135000
  float* gi      = ws + 1965000;     // 720000
  float* w_hhPad = ws + 2685000;     // 77824 (padded 152x512)
                                     // total 2762824 floats ~= 11.05 MB

  prep_kernel<<<1105, 256, 0, stream>>>(conv_w, w_ih, w_hh, conv_wT, w_ihT, w_hhPad);
  conv_kernel<<<(NB*NW*NK + 255)/256, 256, 0, stream>>>(x, conv_b, conv_wT, xc);
  fgat_sisj<<<NB*25, 512, 0, stream>>>(xc, f_lin_w, si_f, sj_f);
  tgat_sisj<<<NB*50, 256, 0, stream>>>(xc, t_lin_w, si_t, sj_t);
  fgat_attn<<<NB*NK, 128, 0, stream>>>(xc, si_f, sj_f, f_lin_b, f_a, f_bias, h_featT);
  tgat_attn<<<NB*NW, 256, 0, stream>>>(xc, si_t, sj_t, t_lin_b, t_a, t_bias, h_temp);
  gi_kernel<<<NB*25, 512, 0, stream>>>(xc, h_featT, h_temp, w_ihT, b_ih, gi);
  gru_kernel<<<NB, 1024, 0, stream>>>(gi, w_hhPad, b_hh, (float*)d_out);
}